// Round 10
// baseline (124.742 us; speedup 1.0000x reference)
//
#include <hip/hip_runtime.h>
#include <hip/hip_bf16.h>

typedef __bf16 bf16x4 __attribute__((ext_vector_type(4)));
typedef __bf16 bf16x8 __attribute__((ext_vector_type(8)));
typedef float f32x4 __attribute__((ext_vector_type(4)));

#define N_PIX 4608      // 2*48*48
#define D_MODEL 512
#define QKV_N 1536
#define KSTR 72

// async global->LDS, 16B per lane. LDS dest is wave-uniform base; HW adds lane*16.
__device__ __forceinline__ void gload_lds16(const void* g, void* l) {
  __builtin_amdgcn_global_load_lds(
      (const __attribute__((address_space(1))) unsigned int*)g,
      (__attribute__((address_space(3))) unsigned int*)l, 16, 0, 0);
}

// ---------------- fused prep: x->bf16 + both weight transposes ----------------
// blocks [0,2304): x convert; [2304,3072): w_qkv^T (q-scale folded); [3072,3328): w_out^T
__global__ __launch_bounds__(256) void prep_kernel(
    const float* __restrict__ x, const float* __restrict__ wq,
    const float* __restrict__ wo, __bf16* __restrict__ xbf,
    __bf16* __restrict__ wqT, __bf16* __restrict__ woT) {
  int b = blockIdx.x, tid = threadIdx.x;
  if (b < 2304) {
    int i = b * 1024 + tid * 4;
    float4 v = *(const float4*)&x[i];
    bf16x4 o = {(__bf16)v.x, (__bf16)v.y, (__bf16)v.z, (__bf16)v.w};
    *(bf16x4*)&xbf[i] = o;
    return;
  }
  __shared__ float tile[32][33];
  const float* src; __bf16* dst; int C, bx, by;
  bool is_wq;
  if (b < 3072) {
    int t = b - 2304; src = wq; dst = wqT; C = 1536;
    bx = (t % 48) * 32; by = (t / 48) * 32; is_wq = true;
  } else {
    int t = b - 3072; src = wo; dst = woT; C = 512;
    bx = (t & 15) * 32; by = (t >> 4) * 32; is_wq = false;
  }
  int tx = tid & 31, ty = tid >> 5;
#pragma unroll
  for (int i = 0; i < 32; i += 8)
    tile[ty + i][tx] = src[(by + ty + i) * C + bx + tx];
  __syncthreads();
#pragma unroll
  for (int i = 0; i < 32; i += 8) {
    int outrow = bx + ty + i;
    float v = tile[tx][ty + i];
    if (is_wq && outrow < 512) v *= 0.125f;  // fold q/sqrt(64)
    dst[outrow * 512 + by + tx] = (__bf16)v;
  }
}

// ---------------- bf16 MFMA GEMM, BK=32, dbuf global_load_lds ----------------
// C[MxN] = A[MxK] * Bt[NxK]^T. Block tile BM x BN, 4 waves (2x2), wave tile
// (BM/2) x (BN/2). Small tiles maximize blocks/CU overlap (latency-bound regime).
// Fragment layouts (verified m89): A[m=lane&15][k=quad*8+j]; Bt[n=lane&15][k=quad*8+j];
// C/D: row=quad*4+reg, col=lane&15.
template <int BM, int BN>
__global__ __launch_bounds__(256) void gemm_kernel(
    const __bf16* __restrict__ A, const __bf16* __restrict__ Bt,
    void* __restrict__ C, int M, int N, int K, int c_is_f32) {
  constexpr int MT = BM / 32, NT = BN / 32, AR = BM / 4, BR = BN / 4;
  __shared__ __bf16 sA[2][BM * 32];
  __shared__ __bf16 sB[2][BN * 32];
  int tid = threadIdx.x;
  int wv = tid >> 6, lane = tid & 63;
  int quad = lane >> 4, r16 = lane & 15;
  int m0 = blockIdx.y * BM, n0 = blockIdx.x * BN;

  int rA = lane >> 2;           // 0..15
  int kc = (lane & 3) * 8;      // 0,8,16,24
  const __bf16* Ag0 = A + (long)(m0 + wv * AR + rA) * K + kc;
  const __bf16* Bg0 = Bt + (long)(n0 + wv * BR + rA) * K + kc;

  int mw = (wv & 1) * (BM / 2), nw = (wv >> 1) * (BN / 2);

  f32x4 acc[MT][NT];
#pragma unroll
  for (int mt = 0; mt < MT; ++mt)
#pragma unroll
    for (int nt = 0; nt < NT; ++nt) acc[mt][nt] = f32x4{0.f, 0.f, 0.f, 0.f};

  auto stage = [&](int buf, int k0) {
    gload_lds16(Ag0 + k0, &sA[buf][(wv * AR) * 32]);
    if (AR == 32)
      gload_lds16(Ag0 + (long)16 * K + k0, &sA[buf][(wv * AR + 16) * 32]);
    gload_lds16(Bg0 + k0, &sB[buf][(wv * BR) * 32]);
    if (BR == 32)
      gload_lds16(Bg0 + (long)16 * K + k0, &sB[buf][(wv * BR + 16) * 32]);
  };

  stage(0, 0);
  int cur = 0;
  for (int k0 = 0; k0 < K; k0 += 32) {
    __syncthreads();
    if (k0 + 32 < K) stage(cur ^ 1, k0 + 32);
    bf16x8 af[MT], bfr[NT];
#pragma unroll
    for (int mt = 0; mt < MT; ++mt)
      af[mt] = *(const bf16x8*)&sA[cur][(mw + mt * 16 + r16) * 32 + quad * 8];
#pragma unroll
    for (int nt = 0; nt < NT; ++nt)
      bfr[nt] = *(const bf16x8*)&sB[cur][(nw + nt * 16 + r16) * 32 + quad * 8];
#pragma unroll
    for (int mt = 0; mt < MT; ++mt)
#pragma unroll
      for (int nt = 0; nt < NT; ++nt)
        acc[mt][nt] = __builtin_amdgcn_mfma_f32_16x16x32_bf16(af[mt], bfr[nt], acc[mt][nt], 0, 0, 0);
    cur ^= 1;
  }

  __bf16* Cb = (__bf16*)C;
  float* Cf = (float*)C;
#pragma unroll
  for (int mt = 0; mt < MT; ++mt)
#pragma unroll
    for (int r = 0; r < 4; ++r) {
      int row = m0 + mw + mt * 16 + quad * 4 + r;
#pragma unroll
      for (int nt = 0; nt < NT; ++nt) {
        int col = n0 + nw + nt * 16 + r16;
        float v = acc[mt][nt][r];
        if (c_is_f32) Cf[(long)row * N + col] = v;
        else          Cb[(long)row * N + col] = (__bf16)v;
      }
    }
}

// ---------------- neighborhood attention, LDS-tiled, 512 threads (R5 form) ----
// Block = 8x8 query tile x 1 head, 8 waves. Stage 14x14 K/V halo (64ch bf16) in LDS.
// 8 lanes per query, each owns 8 channels. Row stride 72 elems (144 B).
// q-scale is pre-folded into w_qkv columns (prep).
__global__ __launch_bounds__(512) void natten_attn_kernel(
    const __bf16* __restrict__ qkv, __bf16* __restrict__ o) {
  __shared__ __bf16 sK[196 * KSTR];
  __shared__ __bf16 sV[196 * KSTR];
  int tid = threadIdx.x;
  int bid = blockIdx.x;                 // 0..575
  int nB = bid / 288;
  int rem = bid - nB * 288;
  int head = rem / 36;
  int tile = rem - head * 36;
  int tr = tile / 6, tc = tile - tr * 6;
  int r0 = tr * 8, c0 = tc * 8;
  int loH = r0 - 3; loH = loH < 0 ? 0 : (loH > 41 ? 41 : loH);
  int loW = c0 - 3; loW = loW < 0 ? 0 : (loW > 41 ? 41 : loW);

  for (int j = tid; j < 196 * 8; j += 512) {
    int rowi = j >> 3, ch = j & 7;
    int rr = rowi / 14, cc = rowi - rr * 14;
    int hh = loH + rr; hh = hh > 47 ? 47 : hh;
    int wp = loW + cc; wp = wp > 47 ? 47 : wp;
    long base = (long)(nB * 2304 + hh * 48 + wp) * QKV_N + head * 64 + ch * 8;
    *(uint4*)&sK[rowi * KSTR + ch * 8] = *(const uint4*)&qkv[base + 512];
    *(uint4*)&sV[rowi * KSTR + ch * 8] = *(const uint4*)&qkv[base + 1024];
  }
  __syncthreads();

  int q = tid >> 3, s = tid & 7;        // 64 queries x 8 channel-slices
  int qr = q >> 3, qc = q & 7;
  int h = r0 + qr, w = c0 + qc;
  int pix = nB * 2304 + h * 48 + w;
  int hs = h - 3; hs = hs < 0 ? 0 : (hs > 41 ? 41 : hs); hs -= loH;
  int ws = w - 3; ws = ws < 0 ? 0 : (ws > 41 ? 41 : ws); ws -= loW;
  int base = (hs * 14 + ws) * KSTR + s * 8;

  bf16x8 q0 = *(const bf16x8*)&qkv[(long)pix * QKV_N + head * 64 + s * 8];
  float qf[8];
#pragma unroll
  for (int t = 0; t < 8; ++t) qf[t] = (float)q0[t];

  float lg[49];
#pragma unroll
  for (int j = 0; j < 49; ++j) {
    int a = j / 7, b = j % 7;
    bf16x8 k0 = *(const bf16x8*)&sK[base + (a * 14 + b) * KSTR];
    float acc = 0.f;
#pragma unroll
    for (int t = 0; t < 8; ++t) acc = fmaf(qf[t], (float)k0[t], acc);
    acc += __shfl_xor(acc, 1);
    acc += __shfl_xor(acc, 2);
    acc += __shfl_xor(acc, 4);
    lg[j] = acc;
  }

  float mx = lg[0];
#pragma unroll
  for (int j = 1; j < 49; ++j) mx = fmaxf(mx, lg[j]);
  float sm = 0.f;
#pragma unroll
  for (int j = 0; j < 49; ++j) { lg[j] = __expf(lg[j] - mx); sm += lg[j]; }
  float inv = 1.f / sm;

  float ov[8];
#pragma unroll
  for (int t = 0; t < 8; ++t) ov[t] = 0.f;
#pragma unroll
  for (int j = 0; j < 49; ++j) {
    int a = j / 7, b = j % 7;
    float pj = lg[j] * inv;
    bf16x8 v0 = *(const bf16x8*)&sV[base + (a * 14 + b) * KSTR];
#pragma unroll
    for (int t = 0; t < 8; ++t) ov[t] = fmaf(pj, (float)v0[t], ov[t]);
  }

  bf16x8 o0;
#pragma unroll
  for (int t = 0; t < 8; ++t) o0[t] = (__bf16)ov[t];
  *(bf16x8*)&o[(long)pix * D_MODEL + head * 64 + s * 8] = o0;
}

// ---------------- launch ----------------

extern "C" void kernel_launch(void* const* d_in, const int* in_sizes, int n_in,
                              void* d_out, int out_size, void* d_ws, size_t ws_size,
                              hipStream_t stream) {
  const float* x = (const float*)d_in[0];      // (2,48,48,512)
  const float* w_qkv = (const float*)d_in[1];  // (512,1536)
  const float* w_out = (const float*)d_in[2];  // (512,512)
  float* out = (float*)d_out;                  // (2,48,48,512)

  __bf16* ws = (__bf16*)d_ws;
  __bf16* xbf   = ws;                                   // 4608*512
  __bf16* wqkvT = xbf + N_PIX * D_MODEL;                // 1536*512
  __bf16* woutT = wqkvT + QKV_N * D_MODEL;              // 512*512
  __bf16* qkvb  = woutT + D_MODEL * D_MODEL;            // 4608*1536
  __bf16* obf   = qkvb + N_PIX * QKV_N;                 // 4608*512

  // prep: x->bf16 (2304 blocks) + w_qkv^T scaled (768) + w_out^T (256)
  prep_kernel<<<3328, 256, 0, stream>>>(x, w_qkv, w_out, xbf, wqkvT, woutT);
  // qkv = xbf @ w_qkv -> bf16 (4608 x 1536); 64x64 tile -> 72x24 = 1728 blocks (6.75/CU)
  gemm_kernel<64, 64><<<dim3(QKV_N / 64, N_PIX / 64), 256, 0, stream>>>(
      xbf, wqkvT, qkvb, N_PIX, QKV_N, D_MODEL, 0);
  // attention -> obf (4608 x 512); R5 dual-buffer form
  natten_attn_kernel<<<576, 512, 0, stream>>>(qkvb, obf);
  // out = obf @ w_out -> fp32; 64x64 tile -> 576 blocks
  gemm_kernel<64, 64><<<dim3(D_MODEL / 64, N_PIX / 64), 256, 0, stream>>>(
      obf, woutT, out, N_PIX, D_MODEL, D_MODEL, 1);
}